// Round 1
// 74.526 us; speedup vs baseline: 1.0110x; 1.0110x over previous
//
#include <hip/hip_runtime.h>
#include <hip/hip_bf16.h>

typedef unsigned short ushort_t;
typedef __attribute__((ext_vector_type(8))) short short8;
typedef __attribute__((ext_vector_type(4))) float floatx4;
typedef __attribute__((ext_vector_type(4))) int intx4;

#define SIG_CH 584
#define KPAD   608      // 19 * 32
#define NKB    76       // KPAD / 8
#define NPROJ  128
#define ASTRIDE 616     // bf16 elems; 616*2 B row stride: 16B aligned, bank-uniform
#define TLEN   4096
#define NWIN   32768    // B*T
#define DROWS  4103     // 8 zero-pad rows + 4095 increment rows
#define WPB    32       // windows per block: LDS 40,640 B <= 40,960 -> 4 blocks/CU

__device__ __forceinline__ ushort_t f2bf(float f) {
    unsigned int v; __builtin_memcpy(&v, &f, 4);
    v += 0x7fffu + ((v >> 16) & 1u);   // round-to-nearest-even
    return (ushort_t)(v >> 16);
}

// HW bf16 convert (compiles to v_cvt_pk_bf16_f32) — 1 instr per pair vs 4/val manual.
__device__ __forceinline__ ushort_t f2bf_hw(float f) {
    __hip_bfloat16 h = __float2bfloat16(f);
    ushort_t u; __builtin_memcpy(&u, &h, 2);
    return u;
}

// One prep kernel: (a) pack W (584x128 fp32) into bf16 (kb,n,kk) K-padded to 608;
// (b) write zero-padded fp32 increments dincP[b][8+ta][k] (rows 0..7 zero).
__global__ void pack_kernel(const float* __restrict__ w, const float* __restrict__ x,
                            ushort_t* __restrict__ wp, float* __restrict__ dincP) {
    int idx = blockIdx.x * 256 + threadIdx.x;
    if (idx < KPAD * NPROJ) {
        int n = idx & (NPROJ - 1);
        int c = idx >> 7;
        ushort_t v = 0;
        if (c < SIG_CH) v = f2bf(w[c * NPROJ + n]);
        wp[((size_t)(c >> 3) * NPROJ + n) * 8 + (c & 7)] = v;
        return;
    }
    int id2 = idx - KPAD * NPROJ;
    if (id2 >= 8 * DROWS * 8) return;
    int k  = id2 & 7;
    int rr = (id2 >> 3) % DROWS;
    int b  = (id2 >> 3) / DROWS;
    float v = 0.f;
    if (rr >= 8) {
        int ta = rr - 8;                       // 0..4094
        const float* xb = x + (size_t)b * TLEN * 8;
        v = xb[(ta + 1) * 8 + k] - xb[ta * 8 + k];
    }
    dincP[((size_t)b * DROWS + rr) * 8 + k] = v;
}

__launch_bounds__(256, 4)
__global__ void sig_gemm_kernel(const float* __restrict__ dincP,
                                const ushort_t* __restrict__ wp,
                                const float* __restrict__ bias,
                                float* __restrict__ out) {
    __shared__ __align__(16) float    s_dinc[WPB + 6][8];  // 38 rows: increments
    __shared__ __align__(16) ushort_t s_A[WPB][ASTRIDE];   // bf16 signature tile (GEMM A)

    const int tid  = threadIdx.x;
    const int blk  = blockIdx.x;               // 1024 blocks — fully co-resident at 4/CU
    const int g0   = blk * WPB;                // first global window index
    const int b    = g0 >> 12;                 // / 4096
    const int t0   = g0 & (TLEN - 1);
    const float* dincB = dincP + (size_t)b * DROWS * 8;

    // ---- phase 0: this block's increments into LDS (pre-padded; float4, one pass) ----
    if (tid < (WPB + 6) * 2) {
        ((floatx4*)s_dinc)[tid] =
            *(const floatx4*)(dincB + (size_t)(t0 + 1) * 8 + tid * 4);
    }
    // zero A pad columns [584, 616)
    for (int idx = tid; idx < WPB * 32; idx += 256) {
        int r = idx >> 5, c = SIG_CH + (idx & 31);
        s_A[r][c] = 0;
    }
    __syncthreads();

    // ---- phase 1: signatures (1 wave = 8 windows; lane (i,j) owns s2[i][j], s3[i][j][:]) ----
    const int wv   = tid >> 6;     // wave 0..3
    const int lane = tid & 63;
    const int li   = lane >> 3;    // i
    const int lj   = lane & 7;     // j

    #pragma unroll 2
    for (int ww = 0; ww < 8; ++ww) {
        const int w = wv * 8 + ww;
        // wave-uniform base for this window's 7x8 increment block -> s_load path
        const int  woff = __builtin_amdgcn_readfirstlane((t0 + 1 + w) * 8);
        const float* dw = dincB + woff;        // dw[st*8 + k]

        float h = 0.f, g = 0.f, s2 = 0.f;
        float s3[8] = {0.f, 0.f, 0.f, 0.f, 0.f, 0.f, 0.f, 0.f};
        #pragma unroll
        for (int st = 0; st < 7; ++st) {
            const float di = s_dinc[w + st][li];   // 8-addr broadcast b32, conflict-free
            const float dj = s_dinc[w + st][lj];
            // c3 = s2_old + 0.5*s1i_old*dj + di*dj/6 ; s2' = s2_old + s1i_old*dj + 0.5*di*dj
            const float c3 = fmaf(dj, fmaf(0.166666667f, di, 0.5f * h), s2);
            s2 = fmaf(dj, fmaf(0.5f, di, h), s2);
            #pragma unroll
            for (int k = 0; k < 8; ++k)
                s3[k] = fmaf(c3, dw[st * 8 + k], s3[k]);   // SGPR operand per fma
            h += di;
            g += dj;
        }
        // write sig row: [s1(8) | s2(64) | s3(512)] as bf16, packed via v_cvt_pk_bf16_f32
        union { ushort_t u[8]; intx4 v; } pk;
        #pragma unroll
        for (int k = 0; k < 8; k += 2) {
            __hip_bfloat162 p2 = __float22bfloat162_rn(float2{s3[k], s3[k + 1]});
            __builtin_memcpy(&pk.u[k], &p2, 4);
        }
        *(intx4*)(&s_A[w][72 + lane * 8]) = pk.v;   // 16B aligned writes
        s_A[w][8 + lane] = f2bf_hw(s2);
        if (lane < 8) s_A[w][lane] = f2bf_hw(g);    // lane<8 has i=0, j=lane -> s1[j]
    }
    __syncthreads();

    // ---- phase 2: GEMM 32x128 @ K=608, wave = 32-col n-slice over all 32 rows ----
    const int lrow  = lane & 15;   // A row within 16-tile / output col within fragment
    const int kgrp  = lane >> 4;   // k-group (k = kgrp*8 + j)
    const int ncol0 = wv * 32 + lrow;

    floatx4 acc[2][2];
    #pragma unroll
    for (int mt = 0; mt < 2; ++mt) {
        acc[mt][0] = floatx4{0.f, 0.f, 0.f, 0.f};
        acc[mt][1] = floatx4{0.f, 0.f, 0.f, 0.f};
    }

    for (int kc = 0; kc < 19; ++kc) {
        const int kb = kc * 4 + kgrp;
        const short8 b0 = *(const short8*)(wp + ((size_t)kb * NPROJ + ncol0) * 8);
        const short8 b1 = *(const short8*)(wp + ((size_t)kb * NPROJ + ncol0 + 16) * 8);
        #pragma unroll
        for (int mt = 0; mt < 2; ++mt) {
            const short8 af = *(const short8*)(&s_A[mt * 16 + lrow][kc * 32 + kgrp * 8]);
            acc[mt][0] = __builtin_amdgcn_mfma_f32_16x16x32_bf16(af, b0, acc[mt][0], 0, 0, 0);
            acc[mt][1] = __builtin_amdgcn_mfma_f32_16x16x32_bf16(af, b1, acc[mt][1], 0, 0, 0);
        }
    }

    const float bias0 = bias[ncol0];
    const float bias1 = bias[ncol0 + 16];
    #pragma unroll
    for (int mt = 0; mt < 2; ++mt) {
        #pragma unroll
        for (int r = 0; r < 4; ++r) {
            const int row = g0 + mt * 16 + kgrp * 4 + r;   // C/D: row = quad*4 + reg
            out[(size_t)row * NPROJ + ncol0]      = acc[mt][0][r] + bias0;
            out[(size_t)row * NPROJ + ncol0 + 16] = acc[mt][1][r] + bias1;
        }
    }
}

extern "C" void kernel_launch(void* const* d_in, const int* in_sizes, int n_in,
                              void* d_out, int out_size, void* d_ws, size_t ws_size,
                              hipStream_t stream) {
    const float* x  = (const float*)d_in[0];   // (8,4096,8) fp32
    const float* w  = (const float*)d_in[1];   // (584,128) fp32
    const float* bp = (const float*)d_in[2];   // (128,) fp32
    ushort_t* wp    = (ushort_t*)d_ws;                         // 155,648 B
    float*    dincP = (float*)((char*)d_ws + 160 * 1024);      // 8*4103*8*4 = 1,050,368 B
    float* out = (float*)d_out;                // (8,4096,128) fp32

    const int prep_total = KPAD * NPROJ + 8 * DROWS * 8;
    hipLaunchKernelGGL(pack_kernel, dim3((prep_total + 255) / 256), dim3(256), 0, stream,
                       w, x, wp, dincP);
    hipLaunchKernelGGL(sig_gemm_kernel, dim3(NWIN / WPB), dim3(256), 0, stream,
                       dincP, wp, bp, out);
}

// Round 2
// 73.982 us; speedup vs baseline: 1.0184x; 1.0074x over previous
//
#include <hip/hip_runtime.h>
#include <hip/hip_bf16.h>

typedef unsigned short ushort_t;
typedef __attribute__((ext_vector_type(8))) short short8;
typedef __attribute__((ext_vector_type(4))) float floatx4;
typedef __attribute__((ext_vector_type(4))) int intx4;

#define SIG_CH 584
#define KPAD   608      // 19 * 32
#define NPROJ  128
#define ASTRIDE 616     // bf16 elems; 616*2 B row stride: 16B aligned, 2-way-max bank spread
#define TLEN   4096
#define NWIN   32768    // B*T
#define DROWS  4103     // 8 zero-pad rows + 4095 increment rows
#define WPB    32       // windows per block

__device__ __forceinline__ ushort_t f2bf(float f) {
    unsigned int v; __builtin_memcpy(&v, &f, 4);
    v += 0x7fffu + ((v >> 16) & 1u);   // round-to-nearest-even
    return (ushort_t)(v >> 16);
}

// HW bf16 convert (v_cvt_pk path)
__device__ __forceinline__ ushort_t f2bf_hw(float f) {
    __hip_bfloat16 h = __float2bfloat16(f);
    ushort_t u; __builtin_memcpy(&u, &h, 2);
    return u;
}

// Prep kernel: (a) pack W (584x128 fp32) -> bf16 (kb,n,kk), K-padded to 608 (scalar, 77,824 thr);
// (b) zero-padded fp32 increments dincP[b][8+ta][k], VECTORIZED: one float4 (half-row) per thread.
#define W_THREADS   (KPAD * NPROJ)         // 77,824
#define D4_THREADS  (8 * DROWS * 2)        // 65,648 half-rows
__global__ void pack_kernel(const float* __restrict__ w, const float* __restrict__ x,
                            ushort_t* __restrict__ wp, float* __restrict__ dincP) {
    int idx = blockIdx.x * 256 + threadIdx.x;
    if (idx < W_THREADS) {
        int n = idx & (NPROJ - 1);
        int c = idx >> 7;
        ushort_t v = 0;
        if (c < SIG_CH) v = f2bf(w[c * NPROJ + n]);
        wp[((size_t)(c >> 3) * NPROJ + n) * 8 + (c & 7)] = v;
        return;
    }
    int id2 = idx - W_THREADS;
    if (id2 >= D4_THREADS) return;
    int h  = id2 & 1;                      // half-row (float4) index
    int rr = (id2 >> 1) % DROWS;
    int b  = (id2 >> 1) / DROWS;
    floatx4 v = floatx4{0.f, 0.f, 0.f, 0.f};
    if (rr >= 8) {
        int ta = rr - 8;                   // 0..4094
        const floatx4* xb4 = (const floatx4*)(x + (size_t)b * TLEN * 8);
        v = xb4[(ta + 1) * 2 + h] - xb4[ta * 2 + h];
    }
    ((floatx4*)dincP)[((size_t)b * DROWS + rr) * 2 + h] = v;
}

__launch_bounds__(256, 3)
__global__ void sig_gemm_kernel(const float* __restrict__ dincP,
                                const ushort_t* __restrict__ wp,
                                const float* __restrict__ bias,
                                float* __restrict__ out) {
    __shared__ __align__(16) float    s_dinc[WPB + 6][8];  // 38 rows: increments
    __shared__ __align__(16) ushort_t s_A[WPB][ASTRIDE];   // bf16 signature tile (GEMM A)

    const int tid  = threadIdx.x;
    const int blk  = blockIdx.x;               // 1024 blocks
    const int g0   = blk * WPB;                // first global window index
    const int b    = g0 >> 12;                 // / 4096
    const int t0   = g0 & (TLEN - 1);
    const float* dincB = dincP + (size_t)b * DROWS * 8;

    // ---- phase 0: this block's increments into LDS (pre-padded; float4, one pass) ----
    if (tid < (WPB + 6) * 2) {
        ((floatx4*)s_dinc)[tid] =
            *(const floatx4*)(dincB + (size_t)(t0 + 1) * 8 + tid * 4);
    }
    // zero A pad columns [584, 616)
    for (int idx = tid; idx < WPB * 32; idx += 256) {
        int r = idx >> 5, c = SIG_CH + (idx & 31);
        s_A[r][c] = 0;
    }
    __syncthreads();

    // ---- phase 1: signatures. Wave = 8 windows, processed in PAIRS sharing an
    //      8-row di/dj register cache (rows w..w+7 cover windows w and w+1). ----
    const int wv   = tid >> 6;     // wave 0..3
    const int lane = tid & 63;
    const int li   = lane >> 3;    // i
    const int lj   = lane & 7;     // j

    #pragma unroll 1
    for (int wp2 = 0; wp2 < 4; ++wp2) {
        const int w = wv * 8 + wp2 * 2;
        // wave-uniform base: rows w..w+7 of this block's increment span -> s_load path
        const int  woff = __builtin_amdgcn_readfirstlane((t0 + 1 + w) * 8);
        const float* dwp = dincB + woff;       // dwp[r*8 + k], r = 0..7

        // register-cache the 8 shared increment rows (constant indices -> stays in VGPRs)
        float diL[8], djL[8];
        #pragma unroll
        for (int r = 0; r < 8; ++r) {
            diL[r] = s_dinc[w + r][li];        // broadcast b32, conflict-free
            djL[r] = s_dinc[w + r][lj];
        }

        float hA = 0.f, gA = 0.f, s2A = 0.f;
        float hB = 0.f, gB = 0.f, s2B = 0.f;
        float s3A[8] = {0.f,0.f,0.f,0.f,0.f,0.f,0.f,0.f};
        float s3B[8] = {0.f,0.f,0.f,0.f,0.f,0.f,0.f,0.f};

        #pragma unroll
        for (int st = 0; st < 7; ++st) {
            // window A (rows st), window B (rows st+1) — interleaved for ILP
            const float diA = diL[st],     djA = djL[st];
            const float diB = diL[st + 1], djB = djL[st + 1];
            const float c3A = fmaf(djA, fmaf(0.166666667f, diA, 0.5f * hA), s2A);
            const float c3B = fmaf(djB, fmaf(0.166666667f, diB, 0.5f * hB), s2B);
            s2A = fmaf(djA, fmaf(0.5f, diA, hA), s2A);
            s2B = fmaf(djB, fmaf(0.5f, diB, hB), s2B);
            #pragma unroll
            for (int k = 0; k < 8; ++k) {
                s3A[k] = fmaf(c3A, dwp[st * 8 + k],       s3A[k]);   // SGPR operand
                s3B[k] = fmaf(c3B, dwp[(st + 1) * 8 + k], s3B[k]);   // shared s_loads (CSE)
            }
            hA += diA; gA += djA;
            hB += diB; gB += djB;
        }

        // write sig rows: [s1(8) | s2(64) | s3(512)] as bf16
        union { ushort_t u[8]; intx4 v; } pkA, pkB;
        #pragma unroll
        for (int k = 0; k < 8; k += 2) {
            __hip_bfloat162 a2 = __float22bfloat162_rn(float2{s3A[k], s3A[k + 1]});
            __hip_bfloat162 b2 = __float22bfloat162_rn(float2{s3B[k], s3B[k + 1]});
            __builtin_memcpy(&pkA.u[k], &a2, 4);
            __builtin_memcpy(&pkB.u[k], &b2, 4);
        }
        *(intx4*)(&s_A[w][72 + lane * 8])     = pkA.v;   // 16B aligned writes
        *(intx4*)(&s_A[w + 1][72 + lane * 8]) = pkB.v;
        s_A[w][8 + lane]     = f2bf_hw(s2A);
        s_A[w + 1][8 + lane] = f2bf_hw(s2B);
        if (lane < 8) {
            s_A[w][lane]     = f2bf_hw(gA);   // lane<8 has i=0, j=lane -> s1[j]
            s_A[w + 1][lane] = f2bf_hw(gB);
        }
    }
    __syncthreads();

    // ---- phase 2: GEMM 32x128 @ K=608, wave = 32-col n-slice over all 32 rows ----
    const int lrow  = lane & 15;   // A row within 16-tile / output col within fragment
    const int kgrp  = lane >> 4;   // k-group (k = kgrp*8 + j)
    const int ncol0 = wv * 32 + lrow;

    floatx4 acc[2][2];
    #pragma unroll
    for (int mt = 0; mt < 2; ++mt) {
        acc[mt][0] = floatx4{0.f, 0.f, 0.f, 0.f};
        acc[mt][1] = floatx4{0.f, 0.f, 0.f, 0.f};
    }

    for (int kc = 0; kc < 19; ++kc) {
        const int kb = kc * 4 + kgrp;
        const short8 b0 = *(const short8*)(wp + ((size_t)kb * NPROJ + ncol0) * 8);
        const short8 b1 = *(const short8*)(wp + ((size_t)kb * NPROJ + ncol0 + 16) * 8);
        #pragma unroll
        for (int mt = 0; mt < 2; ++mt) {
            const short8 af = *(const short8*)(&s_A[mt * 16 + lrow][kc * 32 + kgrp * 8]);
            acc[mt][0] = __builtin_amdgcn_mfma_f32_16x16x32_bf16(af, b0, acc[mt][0], 0, 0, 0);
            acc[mt][1] = __builtin_amdgcn_mfma_f32_16x16x32_bf16(af, b1, acc[mt][1], 0, 0, 0);
        }
    }

    const float bias0 = bias[ncol0];
    const float bias1 = bias[ncol0 + 16];
    #pragma unroll
    for (int mt = 0; mt < 2; ++mt) {
        #pragma unroll
        for (int r = 0; r < 4; ++r) {
            const int row = g0 + mt * 16 + kgrp * 4 + r;   // C/D: row = quad*4 + reg
            out[(size_t)row * NPROJ + ncol0]      = acc[mt][0][r] + bias0;
            out[(size_t)row * NPROJ + ncol0 + 16] = acc[mt][1][r] + bias1;
        }
    }
}

extern "C" void kernel_launch(void* const* d_in, const int* in_sizes, int n_in,
                              void* d_out, int out_size, void* d_ws, size_t ws_size,
                              hipStream_t stream) {
    const float* x  = (const float*)d_in[0];   // (8,4096,8) fp32
    const float* w  = (const float*)d_in[1];   // (584,128) fp32
    const float* bp = (const float*)d_in[2];   // (128,) fp32
    ushort_t* wp    = (ushort_t*)d_ws;                         // 155,648 B
    float*    dincP = (float*)((char*)d_ws + 160 * 1024);      // 8*4103*8*4 = 1,050,368 B
    float* out = (float*)d_out;                // (8,4096,128) fp32

    const int prep_total = W_THREADS + D4_THREADS;             // 143,472
    hipLaunchKernelGGL(pack_kernel, dim3((prep_total + 255) / 256), dim3(256), 0, stream,
                       w, x, wp, dincP);
    hipLaunchKernelGGL(sig_gemm_kernel, dim3(NWIN / WPB), dim3(256), 0, stream,
                       dincP, wp, bp, out);
}